// Round 7
// baseline (2699.181 us; speedup 1.0000x reference)
//
#include <hip/hip_runtime.h>

#define F_DIM   256
#define OVFCAP  8192
#define MAXBUCK 1024
#define BCAP    2560     // bucket capacity (mean 2046, sigma ~45)
#define P1_TILE 8192     // edges per phase-1 block (1024 thr x 8)
#define ELLK    64       // fallback path

struct OvfEdge { int r, c; float v; };

__device__ __forceinline__ unsigned short f32_to_bf16(float x) {
    unsigned u = __float_as_uint(x);
    unsigned r = (u + 0x7FFFu + ((u >> 16) & 1u)) >> 16;  // RNE
    return (unsigned short)r;
}

// ---------- mat_2 f32 -> bf16 ----------
__global__ void cvt_kernel(const float* __restrict__ src,
                           unsigned short* __restrict__ dst, int n4) {
    int t = blockIdx.x * blockDim.x + threadIdx.x;
    if (t >= n4) return;
    float4 f = ((const float4*)src)[t];
    ushort4 o;
    o.x = f32_to_bf16(f.x); o.y = f32_to_bf16(f.y);
    o.z = f32_to_bf16(f.z); o.w = f32_to_bf16(f.w);
    ((ushort4*)dst)[t] = o;
}

// ---------- Phase 1: bucket edges by row>>6, block-aggregated cursors ----------
__global__ void __launch_bounds__(1024)
bucket_kernel(const int* __restrict__ rows, const int* __restrict__ cols,
              const float* __restrict__ vals,
              int* __restrict__ gcur, int2* __restrict__ ebuf,
              int* __restrict__ ovfcnt, OvfEdge* __restrict__ ovf,
              int E, int nbuck) {
    __shared__ int s_cnt[MAXBUCK];
    __shared__ int s_base[MAXBUCK];
    __shared__ int s_cur[MAXBUCK];
    const int t = threadIdx.x;
    for (int i = t; i < nbuck; i += 1024) { s_cnt[i] = 0; s_cur[i] = 0; }
    __syncthreads();

    const long long e0 = (long long)blockIdx.x * P1_TILE;
    int4 r4[2], c4[2]; float4 v4[2];
    #pragma unroll
    for (int k = 0; k < 2; ++k) {
        long long i = e0 + (long long)k * 4096 + (long long)t * 4;
        if (i + 3 < E) {
            r4[k] = *(const int4*)(rows + i);
            c4[k] = *(const int4*)(cols + i);
            v4[k] = *(const float4*)(vals + i);
        } else {
            r4[k] = make_int4(-1, -1, -1, -1);
            c4[k] = make_int4(0, 0, 0, 0);
            v4[k] = make_float4(0.f, 0.f, 0.f, 0.f);
            #pragma unroll
            for (int j = 0; j < 4; ++j) {
                long long ii = i + j;
                if (ii < E) {
                    (&r4[k].x)[j] = rows[ii];
                    (&c4[k].x)[j] = cols[ii];
                    (&v4[k].x)[j] = vals[ii];
                }
            }
        }
        #pragma unroll
        for (int j = 0; j < 4; ++j) {
            int rr = (&r4[k].x)[j];
            if (rr >= 0) atomicAdd(&s_cnt[rr >> 6], 1);   // LDS
        }
    }
    __syncthreads();
    for (int i = t; i < nbuck; i += 1024) {
        int c_ = s_cnt[i];
        s_base[i] = c_ ? atomicAdd(&gcur[i], c_) : 0;     // 1 global atomic per (block,bucket)
    }
    __syncthreads();
    #pragma unroll
    for (int k = 0; k < 2; ++k) {
        #pragma unroll
        for (int j = 0; j < 4; ++j) {
            int rr = (&r4[k].x)[j];
            if (rr < 0) continue;
            int cc = (&c4[k].x)[j];
            float vv = (&v4[k].x)[j];
            int b = rr >> 6;
            int sl = s_base[b] + atomicAdd(&s_cur[b], 1); // LDS
            if (sl < BCAP) {
                ebuf[(long long)b * BCAP + sl] =
                    make_int2((int)(((unsigned)cc << 16) | f32_to_bf16(vv)), rr & 63);
            } else {
                int o = atomicAdd(ovfcnt, 1);
                if (o < OVFCAP) { ovf[o].r = rr; ovf[o].c = cc; ovf[o].v = vv; }
            }
        }
    }
}

// ---------- Phase 2: one block per bucket, 64-row LDS f32 tile ----------
__global__ void __launch_bounds__(1024)
spmm_bucket_kernel(const int* __restrict__ gcur, const int2* __restrict__ ebuf,
                   const unsigned short* __restrict__ mb,
                   float* __restrict__ out, int N) {
    __shared__ float acc[64 * F_DIM];   // 64 KB
    const int t = threadIdx.x;
    #pragma unroll
    for (int q = 0; q < 4; ++q)
        ((float4*)acc)[t + q * 1024] = make_float4(0.f, 0.f, 0.f, 0.f);
    __syncthreads();

    const int b = blockIdx.x;
    const int cnt = min(gcur[b], BCAP);
    const int2* eb = ebuf + (long long)b * BCAP;
    const int wid = t >> 6, lane = t & 63;

    for (int j = wid * 2; j < cnt; j += 32) {
        int2 e0 = eb[j];
        const bool has1 = (j + 1 < cnt);
        int2 e1 = has1 ? eb[j + 1] : e0;
        unsigned p0 = (unsigned)e0.x, p1 = (unsigned)e1.x;
        ushort4 m0 = ((const ushort4*)(mb + ((long long)(p0 >> 16) << 8)))[lane];
        ushort4 m1 = ((const ushort4*)(mb + ((long long)(p1 >> 16) << 8)))[lane];
        float v0 = __uint_as_float((p0 & 0xFFFFu) << 16);
        float* a0 = &acc[e0.y * F_DIM + lane * 4];
        atomicAdd(a0 + 0, v0 * __uint_as_float((unsigned)m0.x << 16));
        atomicAdd(a0 + 1, v0 * __uint_as_float((unsigned)m0.y << 16));
        atomicAdd(a0 + 2, v0 * __uint_as_float((unsigned)m0.z << 16));
        atomicAdd(a0 + 3, v0 * __uint_as_float((unsigned)m0.w << 16));
        if (has1) {
            float v1 = __uint_as_float((p1 & 0xFFFFu) << 16);
            float* a1 = &acc[e1.y * F_DIM + lane * 4];
            atomicAdd(a1 + 0, v1 * __uint_as_float((unsigned)m1.x << 16));
            atomicAdd(a1 + 1, v1 * __uint_as_float((unsigned)m1.y << 16));
            atomicAdd(a1 + 2, v1 * __uint_as_float((unsigned)m1.z << 16));
            atomicAdd(a1 + 3, v1 * __uint_as_float((unsigned)m1.w << 16));
        }
    }
    __syncthreads();
    const int row = t >> 4;
    const int cg  = (t & 15) << 4;
    const long long gr = (long long)b * 64 + row;
    if (gr < N) {
        float4* op = (float4*)(out + gr * F_DIM + cg);
        const float4* ap = (const float4*)(acc + row * F_DIM + cg);
        op[0] = ap[0]; op[1] = ap[1]; op[2] = ap[2]; op[3] = ap[3];
    }
}

// ---------- overflow fixup (expected ~0): f32 atomics ----------
__global__ void ovf_kernel(const int* __restrict__ ovfcnt,
                           const OvfEdge* __restrict__ ovf,
                           const float* __restrict__ mat2,
                           float* __restrict__ out) {
    int cnt = min(*ovfcnt, OVFCAP);
    int lane = threadIdx.x & 63;
    int wid = threadIdx.x >> 6;
    for (int e = wid; e < cnt; e += 4) {
        OvfEdge ed = ovf[e];
        float4 m = ((const float4*)(mat2 + (long long)ed.c * F_DIM))[lane];
        float* dst = out + (long long)ed.r * F_DIM + lane * 4;
        unsafeAtomicAdd(dst + 0, ed.v * m.x);
        unsafeAtomicAdd(dst + 1, ed.v * m.y);
        unsafeAtomicAdd(dst + 2, ed.v * m.z);
        unsafeAtomicAdd(dst + 3, ed.v * m.w);
    }
}

// ---------- Fallback path B: global-cursor ELL (R5) ----------
__device__ __forceinline__ void scatter_one(int r, int c, float v,
                                            int* cursor, unsigned* ell,
                                            int* ovfcnt, OvfEdge* ovf) {
    int pos = atomicAdd(&cursor[r], 1);
    if (pos < ELLK) {
        ell[(long long)r * ELLK + pos] = ((unsigned)c << 16) | f32_to_bf16(v);
    } else {
        int o = atomicAdd(ovfcnt, 1);
        if (o < OVFCAP) { ovf[o].r = r; ovf[o].c = c; ovf[o].v = v; }
    }
}

__global__ void scatter_ell_kernel(const int* __restrict__ rows,
                                   const int* __restrict__ cols,
                                   const float* __restrict__ vals,
                                   int* __restrict__ cursor,
                                   unsigned* __restrict__ ell,
                                   int* __restrict__ ovfcnt,
                                   OvfEdge* __restrict__ ovf, int E) {
    int t = blockIdx.x * blockDim.x + threadIdx.x;
    int i0 = t * 4;
    if (i0 + 3 < E) {
        int4   r = *(const int4*)(rows + i0);
        int4   c = *(const int4*)(cols + i0);
        float4 v = *(const float4*)(vals + i0);
        scatter_one(r.x, c.x, v.x, cursor, ell, ovfcnt, ovf);
        scatter_one(r.y, c.y, v.y, cursor, ell, ovfcnt, ovf);
        scatter_one(r.z, c.z, v.z, cursor, ell, ovfcnt, ovf);
        scatter_one(r.w, c.w, v.w, cursor, ell, ovfcnt, ovf);
    } else {
        for (int i = i0; i < E; ++i)
            scatter_one(rows[i], cols[i], vals[i], cursor, ell, ovfcnt, ovf);
    }
}

template <bool BF16MAT>
__global__ void __launch_bounds__(256)
spmm_ell_kernel(const int* __restrict__ cursor,
                const unsigned* __restrict__ ell,
                const unsigned short* __restrict__ mb,
                const float* __restrict__ mat2,
                float* __restrict__ out, int N) {
    int wave = (int)(((long long)blockIdx.x * blockDim.x + threadIdx.x) >> 6);
    int lane = threadIdx.x & 63;
    if (wave >= N) return;
    int deg = min(cursor[wave], ELLK);
    unsigned pk = (lane < deg) ? ell[(long long)wave * ELLK + lane] : 0u;
    float4 acc = make_float4(0.f, 0.f, 0.f, 0.f);
    int padded = (deg + 7) & ~7;
    for (int j = 0; j < padded; j += 8) {
        #pragma unroll
        for (int k = 0; k < 8; ++k) {
            unsigned e = (unsigned)__shfl((int)pk, j + k);
            int   col = (int)(e >> 16);
            float v   = __uint_as_float((e & 0xFFFFu) << 16);
            if (BF16MAT) {
                ushort4 m = ((const ushort4*)(mb + ((long long)col << 8)))[lane];
                acc.x += v * __uint_as_float((unsigned)m.x << 16);
                acc.y += v * __uint_as_float((unsigned)m.y << 16);
                acc.z += v * __uint_as_float((unsigned)m.z << 16);
                acc.w += v * __uint_as_float((unsigned)m.w << 16);
            } else {
                float4 m = ((const float4*)(mat2 + ((long long)col << 8)))[lane];
                acc.x += v * m.x; acc.y += v * m.y;
                acc.z += v * m.z; acc.w += v * m.w;
            }
        }
    }
    ((float4*)(out + ((long long)wave << 8)))[lane] = acc;
}

// ---------- last resort: pure atomic SpMM ----------
__global__ void spmm_atomic_kernel(const int* __restrict__ rows,
                                   const int* __restrict__ cols,
                                   const float* __restrict__ vals,
                                   const float* __restrict__ mat2,
                                   float* __restrict__ out, int E) {
    long long gid = (long long)blockIdx.x * blockDim.x + threadIdx.x;
    long long e = gid >> 6;
    int q = (int)(gid & 63);
    if (e >= E) return;
    int r = rows[e]; int c = cols[e]; float v = vals[e];
    float4 m = ((const float4*)(mat2 + (long long)c * F_DIM))[q];
    float* dst = out + (long long)r * F_DIM + q * 4;
    unsafeAtomicAdd(dst + 0, v * m.x);
    unsafeAtomicAdd(dst + 1, v * m.y);
    unsafeAtomicAdd(dst + 2, v * m.z);
    unsafeAtomicAdd(dst + 3, v * m.w);
}

extern "C" void kernel_launch(void* const* d_in, const int* in_sizes, int n_in,
                              void* d_out, int out_size, void* d_ws, size_t ws_size,
                              hipStream_t stream) {
    const int*   indices = (const int*)d_in[0];
    const float* vals    = (const float*)d_in[1];
    const float* mat2    = (const float*)d_in[3];
    float*       out     = (float*)d_out;

    const int E  = in_sizes[1];
    const int N  = out_size / F_DIM;
    const int M2 = in_sizes[3];
    const int* rows = indices;
    const int* cols = indices + E;
    const int nbuck = (N + 63) >> 6;

    auto align16 = [](size_t x) { return (x + 15) & ~(size_t)15; };
    char* ws = (char*)d_ws;

    // ---- Path A layout: bucket ----
    size_t o = 0;
    int* gcur    = (int*)(ws + o);
    int* ovfcntA = gcur + nbuck;
    o = align16(o + ((size_t)nbuck + 1) * 4);
    OvfEdge* ovfA = (OvfEdge*)(ws + o); o = align16(o + (size_t)OVFCAP * sizeof(OvfEdge));
    int2* ebuf = (int2*)(ws + o);       o = align16(o + (size_t)nbuck * BCAP * 8);
    unsigned short* mbA = (unsigned short*)(ws + o); o = align16(o + (size_t)M2 * 2);
    size_t need_A = o;

    // ---- Path B/C layout: ELL ----
    o = 0;
    int* cursor  = (int*)(ws + o);
    int* ovfcntB = cursor + N;
    o = align16(o + ((size_t)N + 1) * 4);
    OvfEdge* ovfB = (OvfEdge*)(ws + o); o = align16(o + (size_t)OVFCAP * sizeof(OvfEdge));
    unsigned* ellB = (unsigned*)(ws + o); o = align16(o + (size_t)N * ELLK * 4);
    size_t need_mid = o;
    unsigned short* mbB = (unsigned short*)(ws + o); o = align16(o + (size_t)M2 * 2);
    size_t need_full = o;

    const int vblocks = ((E + 3) / 4 + 255) / 256;
    const int sblocks = (N * 64 + 255) / 256;
    const int cblocks = (M2 / 4 + 255) / 256;
    const int p1blocks = (E + P1_TILE - 1) / P1_TILE;

    if (N <= 65535 && nbuck <= MAXBUCK && ws_size >= need_A) {
        hipMemsetAsync(gcur, 0, ((size_t)nbuck + 1) * 4, stream);
        cvt_kernel<<<cblocks, 256, 0, stream>>>(mat2, mbA, M2 / 4);
        bucket_kernel<<<p1blocks, 1024, 0, stream>>>(rows, cols, vals, gcur, ebuf,
                                                     ovfcntA, ovfA, E, nbuck);
        spmm_bucket_kernel<<<nbuck, 1024, 0, stream>>>(gcur, ebuf, mbA, out, N);
        ovf_kernel<<<1, 256, 0, stream>>>(ovfcntA, ovfA, mat2, out);
    } else if (N <= 65535 && ws_size >= need_full) {
        hipMemsetAsync(cursor, 0, ((size_t)N + 1) * 4, stream);
        cvt_kernel<<<cblocks, 256, 0, stream>>>(mat2, mbB, M2 / 4);
        scatter_ell_kernel<<<vblocks, 256, 0, stream>>>(rows, cols, vals, cursor, ellB, ovfcntB, ovfB, E);
        spmm_ell_kernel<true><<<sblocks, 256, 0, stream>>>(cursor, ellB, mbB, mat2, out, N);
        ovf_kernel<<<1, 256, 0, stream>>>(ovfcntB, ovfB, mat2, out);
    } else if (N <= 65535 && ws_size >= need_mid) {
        hipMemsetAsync(cursor, 0, ((size_t)N + 1) * 4, stream);
        scatter_ell_kernel<<<vblocks, 256, 0, stream>>>(rows, cols, vals, cursor, ellB, ovfcntB, ovfB, E);
        spmm_ell_kernel<false><<<sblocks, 256, 0, stream>>>(cursor, ellB, mbB, mat2, out, N);
        ovf_kernel<<<1, 256, 0, stream>>>(ovfcntB, ovfB, mat2, out);
    } else {
        hipMemsetAsync(d_out, 0, (size_t)out_size * sizeof(float), stream);
        long long total = (long long)E * 64;
        spmm_atomic_kernel<<<(int)((total + 255) / 256), 256, 0, stream>>>(rows, cols, vals, mat2, out, E);
    }
}

// Round 8
// 181.459 us; speedup vs baseline: 14.8749x; 14.8749x over previous
//
#include <hip/hip_runtime.h>

#define F_DIM   256
#define OVFCAP  8192
#define MAXBUCK 1024
#define BCAP    2560     // bucket capacity (mean 2048, sigma ~45)
#define P1_TILE 8192     // edges per phase-1 block (1024 thr x 8)
#define RCAP    64       // per-row LDS slots in phase 2
#define ELLK    64       // fallback path

struct OvfEdge { int r, c; float v; };

__device__ __forceinline__ unsigned short f32_to_bf16(float x) {
    unsigned u = __float_as_uint(x);
    unsigned r = (u + 0x7FFFu + ((u >> 16) & 1u)) >> 16;  // RNE
    return (unsigned short)r;
}

__device__ __forceinline__ void gfma(unsigned e, int lane,
                                     const unsigned short* __restrict__ mb, float4& acc) {
    int   col = (int)(e >> 16);
    float v   = __uint_as_float((e & 0xFFFFu) << 16);
    ushort4 m = ((const ushort4*)(mb + ((long long)col << 8)))[lane];
    acc.x += v * __uint_as_float((unsigned)m.x << 16);
    acc.y += v * __uint_as_float((unsigned)m.y << 16);
    acc.z += v * __uint_as_float((unsigned)m.z << 16);
    acc.w += v * __uint_as_float((unsigned)m.w << 16);
}

// ---------- mat_2 f32 -> bf16 ----------
__global__ void cvt_kernel(const float* __restrict__ src,
                           unsigned short* __restrict__ dst, int n4) {
    int t = blockIdx.x * blockDim.x + threadIdx.x;
    if (t >= n4) return;
    float4 f = ((const float4*)src)[t];
    ushort4 o;
    o.x = f32_to_bf16(f.x); o.y = f32_to_bf16(f.y);
    o.z = f32_to_bf16(f.z); o.w = f32_to_bf16(f.w);
    ((ushort4*)dst)[t] = o;
}

// ---------- Phase 1: bucket edges by row>>6, block-aggregated cursors ----------
__global__ void __launch_bounds__(1024)
bucket_kernel(const int* __restrict__ rows, const int* __restrict__ cols,
              const float* __restrict__ vals,
              int* __restrict__ gcur, int2* __restrict__ ebuf,
              int* __restrict__ ovfcnt, OvfEdge* __restrict__ ovf,
              int E, int nbuck) {
    __shared__ int s_cnt[MAXBUCK];
    __shared__ int s_base[MAXBUCK];
    __shared__ int s_cur[MAXBUCK];
    const int t = threadIdx.x;
    for (int i = t; i < nbuck; i += 1024) { s_cnt[i] = 0; s_cur[i] = 0; }
    __syncthreads();

    const long long e0 = (long long)blockIdx.x * P1_TILE;
    int4 r4[2], c4[2]; float4 v4[2];
    #pragma unroll
    for (int k = 0; k < 2; ++k) {
        long long i = e0 + (long long)k * 4096 + (long long)t * 4;
        if (i + 3 < E) {
            r4[k] = *(const int4*)(rows + i);
            c4[k] = *(const int4*)(cols + i);
            v4[k] = *(const float4*)(vals + i);
        } else {
            r4[k] = make_int4(-1, -1, -1, -1);
            c4[k] = make_int4(0, 0, 0, 0);
            v4[k] = make_float4(0.f, 0.f, 0.f, 0.f);
            #pragma unroll
            for (int j = 0; j < 4; ++j) {
                long long ii = i + j;
                if (ii < E) {
                    (&r4[k].x)[j] = rows[ii];
                    (&c4[k].x)[j] = cols[ii];
                    (&v4[k].x)[j] = vals[ii];
                }
            }
        }
        #pragma unroll
        for (int j = 0; j < 4; ++j) {
            int rr = (&r4[k].x)[j];
            if (rr >= 0) atomicAdd(&s_cnt[rr >> 6], 1);   // LDS
        }
    }
    __syncthreads();
    for (int i = t; i < nbuck; i += 1024) {
        int c_ = s_cnt[i];
        s_base[i] = c_ ? atomicAdd(&gcur[i], c_) : 0;     // 1 global atomic per (block,bucket)
    }
    __syncthreads();
    #pragma unroll
    for (int k = 0; k < 2; ++k) {
        #pragma unroll
        for (int j = 0; j < 4; ++j) {
            int rr = (&r4[k].x)[j];
            if (rr < 0) continue;
            int cc = (&c4[k].x)[j];
            float vv = (&v4[k].x)[j];
            int b = rr >> 6;
            int sl = s_base[b] + atomicAdd(&s_cur[b], 1); // LDS
            if (sl < BCAP) {
                ebuf[(long long)b * BCAP + sl] =
                    make_int2((int)(((unsigned)cc << 16) | f32_to_bf16(vv)), rr & 63);
            } else {
                int o = atomicAdd(ovfcnt, 1);
                if (o < OVFCAP) { ovf[o].r = rr; ovf[o].c = cc; ovf[o].v = vv; }
            }
        }
    }
}

// ---------- Phase 2: one block per bucket; LDS binning (1 int atomic/edge),
// ----------          then R5-style wave-per-row register accumulation ----------
__global__ void __launch_bounds__(1024)
spmm_bucket2_kernel(const int* __restrict__ gcur, const int2* __restrict__ ebuf,
                    const unsigned short* __restrict__ mb,
                    float* __restrict__ out, int N,
                    int* __restrict__ ovfcnt, OvfEdge* __restrict__ ovf) {
    __shared__ unsigned ell_s[64 * RCAP];   // 16 KB, zero-padded
    __shared__ int cur_s[64];
    const int t = threadIdx.x;
    #pragma unroll
    for (int q = 0; q < (64 * RCAP) / 1024; ++q) ell_s[t + q * 1024] = 0u;
    if (t < 64) cur_s[t] = 0;
    __syncthreads();

    const int b = blockIdx.x;
    const int cnt = min(gcur[b], BCAP);
    const int2* eb = ebuf + (long long)b * BCAP;

    // bin: one LDS int atomic + one LDS write per edge
    for (int j = t; j < cnt; j += 1024) {
        int2 e = eb[j];
        int r = e.y;
        int pos = atomicAdd(&cur_s[r], 1);
        if (pos < RCAP) {
            ell_s[(r << 6) | pos] = (unsigned)e.x;
        } else {
            int o = atomicAdd(ovfcnt, 1);
            if (o < OVFCAP) {
                ovf[o].r = b * 64 + r;
                ovf[o].c = (int)((unsigned)e.x >> 16);
                ovf[o].v = __uint_as_float(((unsigned)e.x & 0xFFFFu) << 16);
            }
        }
    }
    __syncthreads();

    // compute: 16 waves x 4 rows, register float4 accumulator, single store
    const int wid = t >> 6, lane = t & 63;
    for (int rr = wid; rr < 64; rr += 16) {
        int deg = min(cur_s[rr], RCAP);
        unsigned pk = ell_s[(rr << 6) | lane];   // zero-padded beyond deg
        float4 acc = make_float4(0.f, 0.f, 0.f, 0.f);
        int padded = (deg + 7) & ~7;
        for (int j = 0; j < padded; j += 8) {
            #pragma unroll
            for (int k = 0; k < 8; ++k) {
                unsigned e = (unsigned)__shfl((int)pk, j + k);
                gfma(e, lane, mb, acc);
            }
        }
        long long gr = (long long)b * 64 + rr;
        if (gr < N) ((float4*)(out + (gr << 8)))[lane] = acc;
    }
}

// ---------- overflow fixup (expected ~0): f32 atomics ----------
__global__ void ovf_kernel(const int* __restrict__ ovfcnt,
                           const OvfEdge* __restrict__ ovf,
                           const float* __restrict__ mat2,
                           float* __restrict__ out) {
    int cnt = min(*ovfcnt, OVFCAP);
    int lane = threadIdx.x & 63;
    int wid = threadIdx.x >> 6;
    for (int e = wid; e < cnt; e += 4) {
        OvfEdge ed = ovf[e];
        float4 m = ((const float4*)(mat2 + (long long)ed.c * F_DIM))[lane];
        float* dst = out + (long long)ed.r * F_DIM + lane * 4;
        unsafeAtomicAdd(dst + 0, ed.v * m.x);
        unsafeAtomicAdd(dst + 1, ed.v * m.y);
        unsafeAtomicAdd(dst + 2, ed.v * m.z);
        unsafeAtomicAdd(dst + 3, ed.v * m.w);
    }
}

// ---------- Fallback path B: global-cursor ELL (R5, proven 264us) ----------
__device__ __forceinline__ void scatter_one(int r, int c, float v,
                                            int* cursor, unsigned* ell,
                                            int* ovfcnt, OvfEdge* ovf) {
    int pos = atomicAdd(&cursor[r], 1);
    if (pos < ELLK) {
        ell[(long long)r * ELLK + pos] = ((unsigned)c << 16) | f32_to_bf16(v);
    } else {
        int o = atomicAdd(ovfcnt, 1);
        if (o < OVFCAP) { ovf[o].r = r; ovf[o].c = c; ovf[o].v = v; }
    }
}

__global__ void scatter_ell_kernel(const int* __restrict__ rows,
                                   const int* __restrict__ cols,
                                   const float* __restrict__ vals,
                                   int* __restrict__ cursor,
                                   unsigned* __restrict__ ell,
                                   int* __restrict__ ovfcnt,
                                   OvfEdge* __restrict__ ovf, int E) {
    int t = blockIdx.x * blockDim.x + threadIdx.x;
    int i0 = t * 4;
    if (i0 + 3 < E) {
        int4   r = *(const int4*)(rows + i0);
        int4   c = *(const int4*)(cols + i0);
        float4 v = *(const float4*)(vals + i0);
        scatter_one(r.x, c.x, v.x, cursor, ell, ovfcnt, ovf);
        scatter_one(r.y, c.y, v.y, cursor, ell, ovfcnt, ovf);
        scatter_one(r.z, c.z, v.z, cursor, ell, ovfcnt, ovf);
        scatter_one(r.w, c.w, v.w, cursor, ell, ovfcnt, ovf);
    } else {
        for (int i = i0; i < E; ++i)
            scatter_one(rows[i], cols[i], vals[i], cursor, ell, ovfcnt, ovf);
    }
}

template <bool BF16MAT>
__global__ void __launch_bounds__(256)
spmm_ell_kernel(const int* __restrict__ cursor,
                const unsigned* __restrict__ ell,
                const unsigned short* __restrict__ mb,
                const float* __restrict__ mat2,
                float* __restrict__ out, int N) {
    int wave = (int)(((long long)blockIdx.x * blockDim.x + threadIdx.x) >> 6);
    int lane = threadIdx.x & 63;
    if (wave >= N) return;
    int deg = min(cursor[wave], ELLK);
    unsigned pk = (lane < deg) ? ell[(long long)wave * ELLK + lane] : 0u;
    float4 acc = make_float4(0.f, 0.f, 0.f, 0.f);
    int padded = (deg + 7) & ~7;
    for (int j = 0; j < padded; j += 8) {
        #pragma unroll
        for (int k = 0; k < 8; ++k) {
            unsigned e = (unsigned)__shfl((int)pk, j + k);
            if (BF16MAT) {
                gfma(e, lane, mb, acc);
            } else {
                int   col = (int)(e >> 16);
                float v   = __uint_as_float((e & 0xFFFFu) << 16);
                float4 m = ((const float4*)(mat2 + ((long long)col << 8)))[lane];
                acc.x += v * m.x; acc.y += v * m.y;
                acc.z += v * m.z; acc.w += v * m.w;
            }
        }
    }
    ((float4*)(out + ((long long)wave << 8)))[lane] = acc;
}

// ---------- last resort: pure atomic SpMM ----------
__global__ void spmm_atomic_kernel(const int* __restrict__ rows,
                                   const int* __restrict__ cols,
                                   const float* __restrict__ vals,
                                   const float* __restrict__ mat2,
                                   float* __restrict__ out, int E) {
    long long gid = (long long)blockIdx.x * blockDim.x + threadIdx.x;
    long long e = gid >> 6;
    int q = (int)(gid & 63);
    if (e >= E) return;
    int r = rows[e]; int c = cols[e]; float v = vals[e];
    float4 m = ((const float4*)(mat2 + (long long)c * F_DIM))[q];
    float* dst = out + (long long)r * F_DIM + q * 4;
    unsafeAtomicAdd(dst + 0, v * m.x);
    unsafeAtomicAdd(dst + 1, v * m.y);
    unsafeAtomicAdd(dst + 2, v * m.z);
    unsafeAtomicAdd(dst + 3, v * m.w);
}

extern "C" void kernel_launch(void* const* d_in, const int* in_sizes, int n_in,
                              void* d_out, int out_size, void* d_ws, size_t ws_size,
                              hipStream_t stream) {
    const int*   indices = (const int*)d_in[0];
    const float* vals    = (const float*)d_in[1];
    const float* mat2    = (const float*)d_in[3];
    float*       out     = (float*)d_out;

    const int E  = in_sizes[1];
    const int N  = out_size / F_DIM;
    const int M2 = in_sizes[3];
    const int* rows = indices;
    const int* cols = indices + E;
    const int nbuck = (N + 63) >> 6;

    auto align16 = [](size_t x) { return (x + 15) & ~(size_t)15; };
    char* ws = (char*)d_ws;

    // ---- Path A layout: bucket ----
    size_t o = 0;
    int* gcur    = (int*)(ws + o);
    int* ovfcntA = gcur + nbuck;
    o = align16(o + ((size_t)nbuck + 1) * 4);
    OvfEdge* ovfA = (OvfEdge*)(ws + o); o = align16(o + (size_t)OVFCAP * sizeof(OvfEdge));
    int2* ebuf = (int2*)(ws + o);       o = align16(o + (size_t)nbuck * BCAP * 8);
    unsigned short* mbA = (unsigned short*)(ws + o); o = align16(o + (size_t)M2 * 2);
    size_t need_A = o;

    // ---- Path B/C layout: ELL ----
    o = 0;
    int* cursor  = (int*)(ws + o);
    int* ovfcntB = cursor + N;
    o = align16(o + ((size_t)N + 1) * 4);
    OvfEdge* ovfB = (OvfEdge*)(ws + o); o = align16(o + (size_t)OVFCAP * sizeof(OvfEdge));
    unsigned* ellB = (unsigned*)(ws + o); o = align16(o + (size_t)N * ELLK * 4);
    size_t need_mid = o;
    unsigned short* mbB = (unsigned short*)(ws + o); o = align16(o + (size_t)M2 * 2);
    size_t need_full = o;

    const int vblocks = ((E + 3) / 4 + 255) / 256;
    const int sblocks = (N * 64 + 255) / 256;
    const int cblocks = (M2 / 4 + 255) / 256;
    const int p1blocks = (E + P1_TILE - 1) / P1_TILE;

    if (N <= 65535 && nbuck <= MAXBUCK && ws_size >= need_A) {
        hipMemsetAsync(gcur, 0, ((size_t)nbuck + 1) * 4, stream);
        cvt_kernel<<<cblocks, 256, 0, stream>>>(mat2, mbA, M2 / 4);
        bucket_kernel<<<p1blocks, 1024, 0, stream>>>(rows, cols, vals, gcur, ebuf,
                                                     ovfcntA, ovfA, E, nbuck);
        spmm_bucket2_kernel<<<nbuck, 1024, 0, stream>>>(gcur, ebuf, mbA, out, N,
                                                        ovfcntA, ovfA);
        ovf_kernel<<<1, 256, 0, stream>>>(ovfcntA, ovfA, mat2, out);
    } else if (N <= 65535 && ws_size >= need_full) {
        hipMemsetAsync(cursor, 0, ((size_t)N + 1) * 4, stream);
        cvt_kernel<<<cblocks, 256, 0, stream>>>(mat2, mbB, M2 / 4);
        scatter_ell_kernel<<<vblocks, 256, 0, stream>>>(rows, cols, vals, cursor, ellB, ovfcntB, ovfB, E);
        spmm_ell_kernel<true><<<sblocks, 256, 0, stream>>>(cursor, ellB, mbB, mat2, out, N);
        ovf_kernel<<<1, 256, 0, stream>>>(ovfcntB, ovfB, mat2, out);
    } else if (N <= 65535 && ws_size >= need_mid) {
        hipMemsetAsync(cursor, 0, ((size_t)N + 1) * 4, stream);
        scatter_ell_kernel<<<vblocks, 256, 0, stream>>>(rows, cols, vals, cursor, ellB, ovfcntB, ovfB, E);
        spmm_ell_kernel<false><<<sblocks, 256, 0, stream>>>(cursor, ellB, mbB, mat2, out, N);
        ovf_kernel<<<1, 256, 0, stream>>>(ovfcntB, ovfB, mat2, out);
    } else {
        hipMemsetAsync(d_out, 0, (size_t)out_size * sizeof(float), stream);
        long long total = (long long)E * 64;
        spmm_atomic_kernel<<<(int)((total + 255) / 256), 256, 0, stream>>>(rows, cols, vals, mat2, out, E);
    }
}

// Round 9
// 164.443 us; speedup vs baseline: 16.4140x; 1.1035x over previous
//
#include <hip/hip_runtime.h>

#define F_DIM   256
#define OVFCAP  8192
#define MAXBUCK 1024
#define BCAP    2560     // bucket capacity (mean 2048, +11 sigma)
#define P1_TILE 8192     // edges per bucket-build block (1024 thr x 8)
#define NPASS   8        // column passes; 50000/8 cols * 512 B = 3.2 MB < 4 MB L2/XCD
#define RCAP    24       // per-row per-pass LDS slots (lambda = 4)
#define ELLK    64       // fallback path

struct OvfEdge { int r, c; float v; };

__device__ __forceinline__ unsigned short f32_to_bf16(float x) {
    unsigned u = __float_as_uint(x);
    unsigned r = (u + 0x7FFFu + ((u >> 16) & 1u)) >> 16;  // RNE
    return (unsigned short)r;
}

__device__ __forceinline__ void gfma(unsigned e, int lane,
                                     const unsigned short* __restrict__ mb, float4& acc) {
    int   col = (int)(e >> 16);
    float v   = __uint_as_float((e & 0xFFFFu) << 16);
    ushort4 m = ((const ushort4*)(mb + ((long long)col << 8)))[lane];
    acc.x += v * __uint_as_float((unsigned)m.x << 16);
    acc.y += v * __uint_as_float((unsigned)m.y << 16);
    acc.z += v * __uint_as_float((unsigned)m.z << 16);
    acc.w += v * __uint_as_float((unsigned)m.w << 16);
}

// ---------- standalone cvt (fallback path B) ----------
__global__ void cvt_kernel(const float* __restrict__ src,
                           unsigned short* __restrict__ dst, int n4) {
    int t = blockIdx.x * blockDim.x + threadIdx.x;
    if (t >= n4) return;
    float4 f = ((const float4*)src)[t];
    ushort4 o;
    o.x = f32_to_bf16(f.x); o.y = f32_to_bf16(f.y);
    o.z = f32_to_bf16(f.z); o.w = f32_to_bf16(f.w);
    ((ushort4*)dst)[t] = o;
}

// ---------- fused build: blocks [0,p1blocks) bucket edges; rest convert mat_2 ----------
__global__ void __launch_bounds__(1024)
build_kernel(const int* __restrict__ rows, const int* __restrict__ cols,
             const float* __restrict__ vals,
             const float* __restrict__ mat2, unsigned short* __restrict__ mb, int n4,
             int* __restrict__ gcur, int2* __restrict__ ebuf,
             int* __restrict__ ovfcnt, OvfEdge* __restrict__ ovf,
             int E, int nbuck, int p1blocks) {
    __shared__ int s_cnt[MAXBUCK];
    __shared__ int s_base[MAXBUCK];
    __shared__ int s_cur[MAXBUCK];
    const int t = threadIdx.x;
    const int bid = blockIdx.x;

    if (bid >= p1blocks) {                       // ---- cvt part ----
        int i = (bid - p1blocks) * 1024 + t;
        if (i < n4) {
            float4 f = ((const float4*)mat2)[i];
            ushort4 o;
            o.x = f32_to_bf16(f.x); o.y = f32_to_bf16(f.y);
            o.z = f32_to_bf16(f.z); o.w = f32_to_bf16(f.w);
            ((ushort4*)mb)[i] = o;
        }
        return;
    }

    // ---- bucket part ----
    for (int i = t; i < nbuck; i += 1024) { s_cnt[i] = 0; s_cur[i] = 0; }
    __syncthreads();

    const long long e0 = (long long)bid * P1_TILE;
    int4 r4[2], c4[2]; float4 v4[2];
    #pragma unroll
    for (int k = 0; k < 2; ++k) {
        long long i = e0 + (long long)k * 4096 + (long long)t * 4;
        if (i + 3 < E) {
            r4[k] = *(const int4*)(rows + i);
            c4[k] = *(const int4*)(cols + i);
            v4[k] = *(const float4*)(vals + i);
        } else {
            r4[k] = make_int4(-1, -1, -1, -1);
            c4[k] = make_int4(0, 0, 0, 0);
            v4[k] = make_float4(0.f, 0.f, 0.f, 0.f);
            #pragma unroll
            for (int j = 0; j < 4; ++j) {
                long long ii = i + j;
                if (ii < E) {
                    (&r4[k].x)[j] = rows[ii];
                    (&c4[k].x)[j] = cols[ii];
                    (&v4[k].x)[j] = vals[ii];
                }
            }
        }
        #pragma unroll
        for (int j = 0; j < 4; ++j) {
            int rr = (&r4[k].x)[j];
            if (rr >= 0) atomicAdd(&s_cnt[rr >> 6], 1);   // LDS
        }
    }
    __syncthreads();
    for (int i = t; i < nbuck; i += 1024) {
        int c_ = s_cnt[i];
        s_base[i] = c_ ? atomicAdd(&gcur[i], c_) : 0;     // 1 global atomic per (block,bucket)
    }
    __syncthreads();
    #pragma unroll
    for (int k = 0; k < 2; ++k) {
        #pragma unroll
        for (int j = 0; j < 4; ++j) {
            int rr = (&r4[k].x)[j];
            if (rr < 0) continue;
            int cc = (&c4[k].x)[j];
            float vv = (&v4[k].x)[j];
            int b = rr >> 6;
            int sl = s_base[b] + atomicAdd(&s_cur[b], 1); // LDS
            if (sl < BCAP) {
                ebuf[(long long)b * BCAP + sl] =
                    make_int2((int)(((unsigned)cc << 16) | f32_to_bf16(vv)), rr & 63);
            } else {
                int o = atomicAdd(ovfcnt, 1);
                if (o < OVFCAP) { ovf[o].r = rr; ovf[o].c = cc; ovf[o].v = vv; }
            }
        }
    }
}

// ---------- Phase 2: one block per 64-row bucket; 8 column passes over L2-resident
// ----------          3.2 MB windows; per-pass LDS re-bin + register accumulation ----------
__global__ void __launch_bounds__(512)
spmm_pass_kernel(const int* __restrict__ gcur, const int2* __restrict__ ebuf,
                 const unsigned short* __restrict__ mb,
                 float* __restrict__ out, int N,
                 int* __restrict__ ovfcnt, OvfEdge* __restrict__ ovf) {
    __shared__ int2 eds[BCAP];              // 20 KB: the bucket's edges, LDS-resident
    __shared__ unsigned ell_s[64 * RCAP];   // 6 KB
    __shared__ int cur_s[64];
    const int t = threadIdx.x;
    const int b = blockIdx.x;
    const int cnt = min(gcur[b], BCAP);
    const int2* eb = ebuf + (long long)b * BCAP;
    for (int j = t; j < cnt; j += 512) eds[j] = eb[j];

    const int wid = t >> 6, lane = t & 63;
    float4 acc[8];
    #pragma unroll
    for (int r = 0; r < 8; ++r) acc[r] = make_float4(0.f, 0.f, 0.f, 0.f);

    const int passw = (N + NPASS - 1) / NPASS;

    for (int p = 0; p < NPASS; ++p) {
        if (t < 64) cur_s[t] = 0;
        __syncthreads();                     // cur_s zeroed (and eds loaded, p==0)
        const int lo = p * passw;
        for (int j = t; j < cnt; j += 512) {
            int2 e = eds[j];
            int col = (int)((unsigned)e.x >> 16);
            if ((unsigned)(col - lo) < (unsigned)passw) {
                int pos = atomicAdd(&cur_s[e.y], 1);
                if (pos < RCAP) {
                    ell_s[e.y * RCAP + pos] = (unsigned)e.x;
                } else {
                    int o = atomicAdd(ovfcnt, 1);
                    if (o < OVFCAP) {
                        ovf[o].r = b * 64 + e.y;
                        ovf[o].c = col;
                        ovf[o].v = __uint_as_float(((unsigned)e.x & 0xFFFFu) << 16);
                    }
                }
            }
        }
        __syncthreads();                     // bins complete
        #pragma unroll
        for (int ri = 0; ri < 8; ++ri) {
            const int rr = wid + (ri << 3);  // wave wid owns rows wid, wid+8, ..., wid+56
            int deg = min(cur_s[rr], RCAP);
            unsigned pk = (lane < deg) ? ell_s[rr * RCAP + lane] : 0u;
            int padded = (deg + 3) & ~3;
            for (int j2 = 0; j2 < padded; j2 += 4) {
                #pragma unroll
                for (int k = 0; k < 4; ++k) {
                    unsigned e = (unsigned)__shfl((int)pk, j2 + k);
                    gfma(e, lane, mb, acc[ri]);   // pad edges: col 0 (L2-hot), v=0
                }
            }
        }
        __syncthreads();                     // compute done before next pass rebins
    }
    #pragma unroll
    for (int ri = 0; ri < 8; ++ri) {
        const int rr = wid + (ri << 3);
        long long gr = (long long)b * 64 + rr;
        if (gr < N) ((float4*)(out + (gr << 8)))[lane] = acc[ri];
    }
}

// ---------- overflow fixup (expected ~0): f32 atomics ----------
__global__ void ovf_kernel(const int* __restrict__ ovfcnt,
                           const OvfEdge* __restrict__ ovf,
                           const float* __restrict__ mat2,
                           float* __restrict__ out) {
    int cnt = min(*ovfcnt, OVFCAP);
    int lane = threadIdx.x & 63;
    int wid = threadIdx.x >> 6;
    for (int e = wid; e < cnt; e += 4) {
        OvfEdge ed = ovf[e];
        float4 m = ((const float4*)(mat2 + (long long)ed.c * F_DIM))[lane];
        float* dst = out + (long long)ed.r * F_DIM + lane * 4;
        unsafeAtomicAdd(dst + 0, ed.v * m.x);
        unsafeAtomicAdd(dst + 1, ed.v * m.y);
        unsafeAtomicAdd(dst + 2, ed.v * m.z);
        unsafeAtomicAdd(dst + 3, ed.v * m.w);
    }
}

// ---------- Fallback path B/C: global-cursor ELL (R5) ----------
__device__ __forceinline__ void scatter_one(int r, int c, float v,
                                            int* cursor, unsigned* ell,
                                            int* ovfcnt, OvfEdge* ovf) {
    int pos = atomicAdd(&cursor[r], 1);
    if (pos < ELLK) {
        ell[(long long)r * ELLK + pos] = ((unsigned)c << 16) | f32_to_bf16(v);
    } else {
        int o = atomicAdd(ovfcnt, 1);
        if (o < OVFCAP) { ovf[o].r = r; ovf[o].c = c; ovf[o].v = v; }
    }
}

__global__ void scatter_ell_kernel(const int* __restrict__ rows,
                                   const int* __restrict__ cols,
                                   const float* __restrict__ vals,
                                   int* __restrict__ cursor,
                                   unsigned* __restrict__ ell,
                                   int* __restrict__ ovfcnt,
                                   OvfEdge* __restrict__ ovf, int E) {
    int t = blockIdx.x * blockDim.x + threadIdx.x;
    int i0 = t * 4;
    if (i0 + 3 < E) {
        int4   r = *(const int4*)(rows + i0);
        int4   c = *(const int4*)(cols + i0);
        float4 v = *(const float4*)(vals + i0);
        scatter_one(r.x, c.x, v.x, cursor, ell, ovfcnt, ovf);
        scatter_one(r.y, c.y, v.y, cursor, ell, ovfcnt, ovf);
        scatter_one(r.z, c.z, v.z, cursor, ell, ovfcnt, ovf);
        scatter_one(r.w, c.w, v.w, cursor, ell, ovfcnt, ovf);
    } else {
        for (int i = i0; i < E; ++i)
            scatter_one(rows[i], cols[i], vals[i], cursor, ell, ovfcnt, ovf);
    }
}

template <bool BF16MAT>
__global__ void __launch_bounds__(256)
spmm_ell_kernel(const int* __restrict__ cursor,
                const unsigned* __restrict__ ell,
                const unsigned short* __restrict__ mb,
                const float* __restrict__ mat2,
                float* __restrict__ out, int N) {
    int wave = (int)(((long long)blockIdx.x * blockDim.x + threadIdx.x) >> 6);
    int lane = threadIdx.x & 63;
    if (wave >= N) return;
    int deg = min(cursor[wave], ELLK);
    unsigned pk = (lane < deg) ? ell[(long long)wave * ELLK + lane] : 0u;
    float4 acc = make_float4(0.f, 0.f, 0.f, 0.f);
    int padded = (deg + 7) & ~7;
    for (int j = 0; j < padded; j += 8) {
        #pragma unroll
        for (int k = 0; k < 8; ++k) {
            unsigned e = (unsigned)__shfl((int)pk, j + k);
            if (BF16MAT) {
                gfma(e, lane, mb, acc);
            } else {
                int   col = (int)(e >> 16);
                float v   = __uint_as_float((e & 0xFFFFu) << 16);
                float4 m = ((const float4*)(mat2 + ((long long)col << 8)))[lane];
                acc.x += v * m.x; acc.y += v * m.y;
                acc.z += v * m.z; acc.w += v * m.w;
            }
        }
    }
    ((float4*)(out + ((long long)wave << 8)))[lane] = acc;
}

// ---------- last resort: pure atomic SpMM ----------
__global__ void spmm_atomic_kernel(const int* __restrict__ rows,
                                   const int* __restrict__ cols,
                                   const float* __restrict__ vals,
                                   const float* __restrict__ mat2,
                                   float* __restrict__ out, int E) {
    long long gid = (long long)blockIdx.x * blockDim.x + threadIdx.x;
    long long e = gid >> 6;
    int q = (int)(gid & 63);
    if (e >= E) return;
    int r = rows[e]; int c = cols[e]; float v = vals[e];
    float4 m = ((const float4*)(mat2 + (long long)c * F_DIM))[q];
    float* dst = out + (long long)r * F_DIM + q * 4;
    unsafeAtomicAdd(dst + 0, v * m.x);
    unsafeAtomicAdd(dst + 1, v * m.y);
    unsafeAtomicAdd(dst + 2, v * m.z);
    unsafeAtomicAdd(dst + 3, v * m.w);
}

extern "C" void kernel_launch(void* const* d_in, const int* in_sizes, int n_in,
                              void* d_out, int out_size, void* d_ws, size_t ws_size,
                              hipStream_t stream) {
    const int*   indices = (const int*)d_in[0];
    const float* vals    = (const float*)d_in[1];
    const float* mat2    = (const float*)d_in[3];
    float*       out     = (float*)d_out;

    const int E  = in_sizes[1];
    const int N  = out_size / F_DIM;
    const int M2 = in_sizes[3];
    const int n4 = M2 / 4;
    const int* rows = indices;
    const int* cols = indices + E;
    const int nbuck = (N + 63) >> 6;

    auto align16 = [](size_t x) { return (x + 15) & ~(size_t)15; };
    char* ws = (char*)d_ws;

    // ---- Path A layout: bucket ----
    size_t o = 0;
    int* gcur    = (int*)(ws + o);
    int* ovfcntA = gcur + nbuck;
    o = align16(o + ((size_t)nbuck + 1) * 4);
    OvfEdge* ovfA = (OvfEdge*)(ws + o); o = align16(o + (size_t)OVFCAP * sizeof(OvfEdge));
    int2* ebuf = (int2*)(ws + o);       o = align16(o + (size_t)nbuck * BCAP * 8);
    unsigned short* mbA = (unsigned short*)(ws + o); o = align16(o + (size_t)M2 * 2);
    size_t need_A = o;

    // ---- Path B/C layout: ELL ----
    o = 0;
    int* cursor  = (int*)(ws + o);
    int* ovfcntB = cursor + N;
    o = align16(o + ((size_t)N + 1) * 4);
    OvfEdge* ovfB = (OvfEdge*)(ws + o); o = align16(o + (size_t)OVFCAP * sizeof(OvfEdge));
    unsigned* ellB = (unsigned*)(ws + o); o = align16(o + (size_t)N * ELLK * 4);
    size_t need_mid = o;
    unsigned short* mbB = (unsigned short*)(ws + o); o = align16(o + (size_t)M2 * 2);
    size_t need_full = o;

    const int vblocks = ((E + 3) / 4 + 255) / 256;
    const int sblocks = (N * 64 + 255) / 256;
    const int cblocks = (n4 + 255) / 256;
    const int p1blocks = (E + P1_TILE - 1) / P1_TILE;

    if (N <= 65535 && nbuck <= MAXBUCK && ws_size >= need_A) {
        hipMemsetAsync(gcur, 0, ((size_t)nbuck + 1) * 4, stream);
        int bgrid = p1blocks + (n4 + 1023) / 1024;
        build_kernel<<<bgrid, 1024, 0, stream>>>(rows, cols, vals, mat2, mbA, n4,
                                                 gcur, ebuf, ovfcntA, ovfA, E, nbuck, p1blocks);
        spmm_pass_kernel<<<nbuck, 512, 0, stream>>>(gcur, ebuf, mbA, out, N, ovfcntA, ovfA);
        ovf_kernel<<<1, 256, 0, stream>>>(ovfcntA, ovfA, mat2, out);
    } else if (N <= 65535 && ws_size >= need_full) {
        hipMemsetAsync(cursor, 0, ((size_t)N + 1) * 4, stream);
        cvt_kernel<<<cblocks, 256, 0, stream>>>(mat2, mbB, n4);
        scatter_ell_kernel<<<vblocks, 256, 0, stream>>>(rows, cols, vals, cursor, ellB, ovfcntB, ovfB, E);
        spmm_ell_kernel<true><<<sblocks, 256, 0, stream>>>(cursor, ellB, mbB, mat2, out, N);
        ovf_kernel<<<1, 256, 0, stream>>>(ovfcntB, ovfB, mat2, out);
    } else if (N <= 65535 && ws_size >= need_mid) {
        hipMemsetAsync(cursor, 0, ((size_t)N + 1) * 4, stream);
        scatter_ell_kernel<<<vblocks, 256, 0, stream>>>(rows, cols, vals, cursor, ellB, ovfcntB, ovfB, E);
        spmm_ell_kernel<false><<<sblocks, 256, 0, stream>>>(cursor, ellB, mbB, mat2, out, N);
        ovf_kernel<<<1, 256, 0, stream>>>(ovfcntB, ovfB, mat2, out);
    } else {
        hipMemsetAsync(d_out, 0, (size_t)out_size * sizeof(float), stream);
        long long total = (long long)E * 64;
        spmm_atomic_kernel<<<(int)((total + 255) / 256), 256, 0, stream>>>(rows, cols, vals, mat2, out, E);
    }
}

// Round 10
// 144.794 us; speedup vs baseline: 18.6415x; 1.1357x over previous
//
#include <hip/hip_runtime.h>

#define F_DIM   256
#define OVFCAP  8192
#define MAXBUCK 1024
#define BCAP    2560     // bucket capacity (mean 2048, +11 sigma)
#define P1_TILE 8192     // edges per bucket-build block (1024 thr x 8)
#define NPASS   8        // column passes; 50000/8 cols * 512 B = 3.2 MB < 4 MB L2/XCD
#define RCAP    24       // per-row per-pass LDS slots (lambda = 4)
#define ELLK    64       // fallback path

struct OvfEdge { int r, c; float v; };

__device__ __forceinline__ unsigned short f32_to_bf16(float x) {
    unsigned u = __float_as_uint(x);
    unsigned r = (u + 0x7FFFu + ((u >> 16) & 1u)) >> 16;  // RNE
    return (unsigned short)r;
}

__device__ __forceinline__ void gfma(unsigned e, int lane,
                                     const unsigned short* __restrict__ mb, float4& acc) {
    int   col = (int)(e >> 16);
    float v   = __uint_as_float((e & 0xFFFFu) << 16);
    ushort4 m = ((const ushort4*)(mb + ((long long)col << 8)))[lane];
    acc.x += v * __uint_as_float((unsigned)m.x << 16);
    acc.y += v * __uint_as_float((unsigned)m.y << 16);
    acc.z += v * __uint_as_float((unsigned)m.z << 16);
    acc.w += v * __uint_as_float((unsigned)m.w << 16);
}

// ---------- standalone cvt (fallback path B) ----------
__global__ void cvt_kernel(const float* __restrict__ src,
                           unsigned short* __restrict__ dst, int n4) {
    int t = blockIdx.x * blockDim.x + threadIdx.x;
    if (t >= n4) return;
    float4 f = ((const float4*)src)[t];
    ushort4 o;
    o.x = f32_to_bf16(f.x); o.y = f32_to_bf16(f.y);
    o.z = f32_to_bf16(f.z); o.w = f32_to_bf16(f.w);
    ((ushort4*)dst)[t] = o;
}

// ---------- fused build: blocks [0,p1blocks) bucket edges; rest convert mat_2 ----------
__global__ void __launch_bounds__(1024)
build_kernel(const int* __restrict__ rows, const int* __restrict__ cols,
             const float* __restrict__ vals,
             const float* __restrict__ mat2, unsigned short* __restrict__ mb, int n4,
             int* __restrict__ gcur, int2* __restrict__ ebuf,
             int* __restrict__ ovfcnt, OvfEdge* __restrict__ ovf,
             int E, int nbuck, int p1blocks) {
    __shared__ int s_cnt[MAXBUCK];
    __shared__ int s_base[MAXBUCK];
    __shared__ int s_cur[MAXBUCK];
    const int t = threadIdx.x;
    const int bid = blockIdx.x;

    if (bid >= p1blocks) {                       // ---- cvt part ----
        int i = (bid - p1blocks) * 1024 + t;
        if (i < n4) {
            float4 f = ((const float4*)mat2)[i];
            ushort4 o;
            o.x = f32_to_bf16(f.x); o.y = f32_to_bf16(f.y);
            o.z = f32_to_bf16(f.z); o.w = f32_to_bf16(f.w);
            ((ushort4*)mb)[i] = o;
        }
        return;
    }

    // ---- bucket part ----
    for (int i = t; i < nbuck; i += 1024) { s_cnt[i] = 0; s_cur[i] = 0; }
    __syncthreads();

    const long long e0 = (long long)bid * P1_TILE;
    int4 r4[2], c4[2]; float4 v4[2];
    #pragma unroll
    for (int k = 0; k < 2; ++k) {
        long long i = e0 + (long long)k * 4096 + (long long)t * 4;
        if (i + 3 < E) {
            r4[k] = *(const int4*)(rows + i);
            c4[k] = *(const int4*)(cols + i);
            v4[k] = *(const float4*)(vals + i);
        } else {
            r4[k] = make_int4(-1, -1, -1, -1);
            c4[k] = make_int4(0, 0, 0, 0);
            v4[k] = make_float4(0.f, 0.f, 0.f, 0.f);
            #pragma unroll
            for (int j = 0; j < 4; ++j) {
                long long ii = i + j;
                if (ii < E) {
                    (&r4[k].x)[j] = rows[ii];
                    (&c4[k].x)[j] = cols[ii];
                    (&v4[k].x)[j] = vals[ii];
                }
            }
        }
        #pragma unroll
        for (int j = 0; j < 4; ++j) {
            int rr = (&r4[k].x)[j];
            if (rr >= 0) atomicAdd(&s_cnt[rr >> 6], 1);   // LDS
        }
    }
    __syncthreads();
    for (int i = t; i < nbuck; i += 1024) {
        int c_ = s_cnt[i];
        s_base[i] = c_ ? atomicAdd(&gcur[i], c_) : 0;     // 1 global atomic per (block,bucket)
    }
    __syncthreads();
    #pragma unroll
    for (int k = 0; k < 2; ++k) {
        #pragma unroll
        for (int j = 0; j < 4; ++j) {
            int rr = (&r4[k].x)[j];
            if (rr < 0) continue;
            int cc = (&c4[k].x)[j];
            float vv = (&v4[k].x)[j];
            int b = rr >> 6;
            int sl = s_base[b] + atomicAdd(&s_cur[b], 1); // LDS
            if (sl < BCAP) {
                ebuf[(long long)b * BCAP + sl] =
                    make_int2((int)(((unsigned)cc << 16) | f32_to_bf16(vv)), rr & 63);
            } else {
                int o = atomicAdd(ovfcnt, 1);
                if (o < OVFCAP) { ovf[o].r = rr; ovf[o].c = cc; ovf[o].v = vv; }
            }
        }
    }
}

// ---------- Phase 2: one block per 64-row bucket; 8 column passes over L2-resident
// windows; bin(p+1) overlapped with compute(p) via double-buffered LDS ELL;
// explicit 4-deep load batching; __launch_bounds__(512,8) -> <=64 VGPR, 4 blk/CU,
// all 782 blocks co-resident. ----------
__global__ void __launch_bounds__(512, 8)
spmm_pass_kernel(const int* __restrict__ gcur, const int2* __restrict__ ebuf,
                 const unsigned short* __restrict__ mb,
                 float* __restrict__ out, int N,
                 int* __restrict__ ovfcnt, OvfEdge* __restrict__ ovf) {
    __shared__ int2 eds[BCAP];                 // 20 KB
    __shared__ unsigned ell_s[2][64 * RCAP];   // 12 KB
    __shared__ int cur_s[2][64];
    const int t = threadIdx.x;
    const int b = blockIdx.x;
    const int cnt = min(gcur[b], BCAP);
    const int2* eb = ebuf + (long long)b * BCAP;
    for (int j = t; j < cnt; j += 512) eds[j] = eb[j];
    if (t < 128) ((int*)cur_s)[t] = 0;
    __syncthreads();

    const int passw = (N + NPASS - 1) / NPASS;

    auto bin = [&](int p, int buf) {
        const int lo = p * passw;
        for (int j = t; j < cnt; j += 512) {
            int2 e = eds[j];
            int col = (int)((unsigned)e.x >> 16);
            if ((unsigned)(col - lo) < (unsigned)passw) {
                int pos = atomicAdd(&cur_s[buf][e.y], 1);
                if (pos < RCAP) {
                    ell_s[buf][e.y * RCAP + pos] = (unsigned)e.x;
                } else {
                    int o = atomicAdd(ovfcnt, 1);
                    if (o < OVFCAP) {
                        ovf[o].r = b * 64 + e.y;
                        ovf[o].c = col;
                        ovf[o].v = __uint_as_float(((unsigned)e.x & 0xFFFFu) << 16);
                    }
                }
            }
        }
    };

    bin(0, 0);
    __syncthreads();

    const int wid = t >> 6, lane = t & 63;
    float4 acc[8];
    #pragma unroll
    for (int r = 0; r < 8; ++r) acc[r] = make_float4(0.f, 0.f, 0.f, 0.f);

    for (int p = 0; p < NPASS; ++p) {
        const int cur = p & 1, nxt = cur ^ 1;
        if (p + 1 < NPASS) bin(p + 1, nxt);    // LDS work; overlaps gathers below

        const unsigned pad = (unsigned)(p * passw) << 16;   // v=0, col=window base (hot)
        #pragma unroll
        for (int ri = 0; ri < 8; ++ri) {
            const int rr = wid + (ri << 3);
            int deg = min(cur_s[cur][rr], RCAP);
            unsigned pk = (lane < deg) ? ell_s[cur][rr * RCAP + lane] : pad;
            int padded = (deg + 3) & ~3;
            for (int j2 = 0; j2 < padded; j2 += 4) {
                ushort4 m[4]; float v[4];
                #pragma unroll
                for (int k = 0; k < 4; ++k) {           // issue 4 independent gathers
                    unsigned e = (unsigned)__shfl((int)pk, j2 + k);
                    v[k] = __uint_as_float((e & 0xFFFFu) << 16);
                    m[k] = ((const ushort4*)(mb + ((long long)(e >> 16) << 8)))[lane];
                }
                #pragma unroll
                for (int k = 0; k < 4; ++k) {           // consume
                    acc[ri].x += v[k] * __uint_as_float((unsigned)m[k].x << 16);
                    acc[ri].y += v[k] * __uint_as_float((unsigned)m[k].y << 16);
                    acc[ri].z += v[k] * __uint_as_float((unsigned)m[k].z << 16);
                    acc[ri].w += v[k] * __uint_as_float((unsigned)m[k].w << 16);
                }
            }
        }
        __syncthreads();                       // bins(p+1) ready; ell_s[cur] free
        if (t < 64) cur_s[cur][t] = 0;         // recycle counters for pass p+2
        __syncthreads();
    }

    #pragma unroll
    for (int ri = 0; ri < 8; ++ri) {
        const int rr = wid + (ri << 3);
        long long gr = (long long)b * 64 + rr;
        if (gr < N) ((float4*)(out + (gr << 8)))[lane] = acc[ri];
    }
}

// ---------- overflow fixup (expected ~0): f32 atomics ----------
__global__ void ovf_kernel(const int* __restrict__ ovfcnt,
                           const OvfEdge* __restrict__ ovf,
                           const float* __restrict__ mat2,
                           float* __restrict__ out) {
    int cnt = min(*ovfcnt, OVFCAP);
    int lane = threadIdx.x & 63;
    int wid = threadIdx.x >> 6;
    for (int e = wid; e < cnt; e += 4) {
        OvfEdge ed = ovf[e];
        float4 m = ((const float4*)(mat2 + (long long)ed.c * F_DIM))[lane];
        float* dst = out + (long long)ed.r * F_DIM + lane * 4;
        unsafeAtomicAdd(dst + 0, ed.v * m.x);
        unsafeAtomicAdd(dst + 1, ed.v * m.y);
        unsafeAtomicAdd(dst + 2, ed.v * m.z);
        unsafeAtomicAdd(dst + 3, ed.v * m.w);
    }
}

// ---------- Fallback path B/C: global-cursor ELL (R5) ----------
__device__ __forceinline__ void scatter_one(int r, int c, float v,
                                            int* cursor, unsigned* ell,
                                            int* ovfcnt, OvfEdge* ovf) {
    int pos = atomicAdd(&cursor[r], 1);
    if (pos < ELLK) {
        ell[(long long)r * ELLK + pos] = ((unsigned)c << 16) | f32_to_bf16(v);
    } else {
        int o = atomicAdd(ovfcnt, 1);
        if (o < OVFCAP) { ovf[o].r = r; ovf[o].c = c; ovf[o].v = v; }
    }
}

__global__ void scatter_ell_kernel(const int* __restrict__ rows,
                                   const int* __restrict__ cols,
                                   const float* __restrict__ vals,
                                   int* __restrict__ cursor,
                                   unsigned* __restrict__ ell,
                                   int* __restrict__ ovfcnt,
                                   OvfEdge* __restrict__ ovf, int E) {
    int t = blockIdx.x * blockDim.x + threadIdx.x;
    int i0 = t * 4;
    if (i0 + 3 < E) {
        int4   r = *(const int4*)(rows + i0);
        int4   c = *(const int4*)(cols + i0);
        float4 v = *(const float4*)(vals + i0);
        scatter_one(r.x, c.x, v.x, cursor, ell, ovfcnt, ovf);
        scatter_one(r.y, c.y, v.y, cursor, ell, ovfcnt, ovf);
        scatter_one(r.z, c.z, v.z, cursor, ell, ovfcnt, ovf);
        scatter_one(r.w, c.w, v.w, cursor, ell, ovfcnt, ovf);
    } else {
        for (int i = i0; i < E; ++i)
            scatter_one(rows[i], cols[i], vals[i], cursor, ell, ovfcnt, ovf);
    }
}

template <bool BF16MAT>
__global__ void __launch_bounds__(256)
spmm_ell_kernel(const int* __restrict__ cursor,
                const unsigned* __restrict__ ell,
                const unsigned short* __restrict__ mb,
                const float* __restrict__ mat2,
                float* __restrict__ out, int N) {
    int wave = (int)(((long long)blockIdx.x * blockDim.x + threadIdx.x) >> 6);
    int lane = threadIdx.x & 63;
    if (wave >= N) return;
    int deg = min(cursor[wave], ELLK);
    unsigned pk = (lane < deg) ? ell[(long long)wave * ELLK + lane] : 0u;
    float4 acc = make_float4(0.f, 0.f, 0.f, 0.f);
    int padded = (deg + 7) & ~7;
    for (int j = 0; j < padded; j += 8) {
        #pragma unroll
        for (int k = 0; k < 8; ++k) {
            unsigned e = (unsigned)__shfl((int)pk, j + k);
            if (BF16MAT) {
                gfma(e, lane, mb, acc);
            } else {
                int   col = (int)(e >> 16);
                float v   = __uint_as_float((e & 0xFFFFu) << 16);
                float4 m = ((const float4*)(mat2 + ((long long)col << 8)))[lane];
                acc.x += v * m.x; acc.y += v * m.y;
                acc.z += v * m.z; acc.w += v * m.w;
            }
        }
    }
    ((float4*)(out + ((long long)wave << 8)))[lane] = acc;
}

// ---------- last resort: pure atomic SpMM ----------
__global__ void spmm_atomic_kernel(const int* __restrict__ rows,
                                   const int* __restrict__ cols,
                                   const float* __restrict__ vals,
                                   const float* __restrict__ mat2,
                                   float* __restrict__ out, int E) {
    long long gid = (long long)blockIdx.x * blockDim.x + threadIdx.x;
    long long e = gid >> 6;
    int q = (int)(gid & 63);
    if (e >= E) return;
    int r = rows[e]; int c = cols[e]; float v = vals[e];
    float4 m = ((const float4*)(mat2 + (long long)c * F_DIM))[q];
    float* dst = out + (long long)r * F_DIM + q * 4;
    unsafeAtomicAdd(dst + 0, v * m.x);
    unsafeAtomicAdd(dst + 1, v * m.y);
    unsafeAtomicAdd(dst + 2, v * m.z);
    unsafeAtomicAdd(dst + 3, v * m.w);
}

extern "C" void kernel_launch(void* const* d_in, const int* in_sizes, int n_in,
                              void* d_out, int out_size, void* d_ws, size_t ws_size,
                              hipStream_t stream) {
    const int*   indices = (const int*)d_in[0];
    const float* vals    = (const float*)d_in[1];
    const float* mat2    = (const float*)d_in[3];
    float*       out     = (float*)d_out;

    const int E  = in_sizes[1];
    const int N  = out_size / F_DIM;
    const int M2 = in_sizes[3];
    const int n4 = M2 / 4;
    const int* rows = indices;
    const int* cols = indices + E;
    const int nbuck = (N + 63) >> 6;

    auto align16 = [](size_t x) { return (x + 15) & ~(size_t)15; };
    char* ws = (char*)d_ws;

    // ---- Path A layout: bucket ----
    size_t o = 0;
    int* gcur    = (int*)(ws + o);
    int* ovfcntA = gcur + nbuck;
    o = align16(o + ((size_t)nbuck + 1) * 4);
    OvfEdge* ovfA = (OvfEdge*)(ws + o); o = align16(o + (size_t)OVFCAP * sizeof(OvfEdge));
    int2* ebuf = (int2*)(ws + o);       o = align16(o + (size_t)nbuck * BCAP * 8);
    unsigned short* mbA = (unsigned short*)(ws + o); o = align16(o + (size_t)M2 * 2);
    size_t need_A = o;

    // ---- Path B/C layout: ELL ----
    o = 0;
    int* cursor  = (int*)(ws + o);
    int* ovfcntB = cursor + N;
    o = align16(o + ((size_t)N + 1) * 4);
    OvfEdge* ovfB = (OvfEdge*)(ws + o); o = align16(o + (size_t)OVFCAP * sizeof(OvfEdge));
    unsigned* ellB = (unsigned*)(ws + o); o = align16(o + (size_t)N * ELLK * 4);
    size_t need_mid = o;
    unsigned short* mbB = (unsigned short*)(ws + o); o = align16(o + (size_t)M2 * 2);
    size_t need_full = o;

    const int vblocks = ((E + 3) / 4 + 255) / 256;
    const int sblocks = (N * 64 + 255) / 256;
    const int cblocks = (n4 + 255) / 256;
    const int p1blocks = (E + P1_TILE - 1) / P1_TILE;

    if (N <= 65535 && nbuck <= MAXBUCK && ws_size >= need_A) {
        hipMemsetAsync(gcur, 0, ((size_t)nbuck + 1) * 4, stream);
        int bgrid = p1blocks + (n4 + 1023) / 1024;
        build_kernel<<<bgrid, 1024, 0, stream>>>(rows, cols, vals, mat2, mbA, n4,
                                                 gcur, ebuf, ovfcntA, ovfA, E, nbuck, p1blocks);
        spmm_pass_kernel<<<nbuck, 512, 0, stream>>>(gcur, ebuf, mbA, out, N, ovfcntA, ovfA);
        ovf_kernel<<<1, 256, 0, stream>>>(ovfcntA, ovfA, mat2, out);
    } else if (N <= 65535 && ws_size >= need_full) {
        hipMemsetAsync(cursor, 0, ((size_t)N + 1) * 4, stream);
        cvt_kernel<<<cblocks, 256, 0, stream>>>(mat2, mbB, n4);
        scatter_ell_kernel<<<vblocks, 256, 0, stream>>>(rows, cols, vals, cursor, ellB, ovfcntB, ovfB, E);
        spmm_ell_kernel<true><<<sblocks, 256, 0, stream>>>(cursor, ellB, mbB, mat2, out, N);
        ovf_kernel<<<1, 256, 0, stream>>>(ovfcntB, ovfB, mat2, out);
    } else if (N <= 65535 && ws_size >= need_mid) {
        hipMemsetAsync(cursor, 0, ((size_t)N + 1) * 4, stream);
        scatter_ell_kernel<<<vblocks, 256, 0, stream>>>(rows, cols, vals, cursor, ellB, ovfcntB, ovfB, E);
        spmm_ell_kernel<false><<<sblocks, 256, 0, stream>>>(cursor, ellB, mbB, mat2, out, N);
        ovf_kernel<<<1, 256, 0, stream>>>(ovfcntB, ovfB, mat2, out);
    } else {
        hipMemsetAsync(d_out, 0, (size_t)out_size * sizeof(float), stream);
        long long total = (long long)E * 64;
        spmm_atomic_kernel<<<(int)((total + 255) / 256), 256, 0, stream>>>(rows, cols, vals, mat2, out, E);
    }
}